// Round 3
// baseline (1529.020 us; speedup 1.0000x reference)
//
#include <hip/hip_runtime.h>

// LaplacianBuilder: N=1024, E=16384 triu edges, D=16.
// Output L = (16384)^2 f32 = 1 GiB, block-sparse (33792 nonzero 16x16 blocks).
// Round 3: single fused fill+scatter pass — every output byte written exactly
// once (coalesced float4), nonzero blocks computed on the fly from a 2 MB
// short block-index table. No atomics, no separate zero pass, no CSR.
//   idx[r*N+c] = +(e+1)  -> block = -s * (Mf_e^T Mt_e)         (r,c) triu
//   idx[c*N+r] = -(e+1)  -> block = -s * (Mf_e^T Mt_e)^T
//   diag block computed by the wg owning column r of block-row r.

#define NN 1024
#define EE 16384
#define LDim 16384

// ---- ws layout: short idx[1024*1024] (2 MB) ----

__global__ __launch_bounds__(256) void zero_idx(int4* __restrict__ idx4) {
    idx4[blockIdx.x * 256 + threadIdx.x] = make_int4(0, 0, 0, 0);   // grid 512
}

__global__ __launch_bounds__(256) void scatter_idx(const int* __restrict__ edge_index,
                                                   short* __restrict__ idx) {
    const int e = blockIdx.x * 256 + threadIdx.x;   // grid 64 -> e in [0,E)
    const int r = edge_index[e];                    // edge_index[0][e] (row, r<c)
    const int c = edge_index[2 * EE + e];           // edge_index[1][e] (col)
    idx[r * NN + c] = (short)(e + 1);
    idx[c * NN + r] = (short)(-(e + 1));
}

__global__ __launch_bounds__(256) void fused_fill(
    const float* __restrict__ maps,      // [2E][16][16]
    const float* __restrict__ degrees,   // [N]
    const short* __restrict__ idx,       // [N][N]
    float* __restrict__ out)             // [16384][16384]
{
    __shared__ short sIdx[NN];     // full block-row of the index table
    __shared__ float sDiag[256];   // diagonal block (filled by owning wg only)
    const int t = threadIdx.x;
    const int r = blockIdx.x >> 2;     // block-row
    const int seg = blockIdx.x & 3;    // 4096-column segment

    // load full idx row: 1024 shorts = 256 threads x int2
    ((int2*)sIdx)[t] = ((const int2*)(idx + (size_t)r * NN))[t];
    __syncthreads();

    const float dinv_r = rsqrtf(degrees[r] * 16.0f + 1.0f);

    if (seg == (r >> 8)) {
        // this wg owns block-column r: compute the diagonal block
        const int j = t >> 4, k = t & 15;
        float acc = 0.0f;
        for (int c2 = 0; c2 < NN; ++c2) {
            const int id = sIdx[c2];
            if (id != 0) {
                // directed edge with src==r: maps[e] if r is the triu row,
                // maps[e+E] if r is the triu col.
                const int m = (id > 0) ? (id - 1) : (-id - 1 + EE);
                const float* M = maps + (size_t)m * 256;
                #pragma unroll
                for (int i = 0; i < 16; ++i)
                    acc += M[i * 16 + j] * M[i * 16 + k];
            }
        }
        sDiag[t] = acc * dinv_r * dinv_r;
    }
    __syncthreads();

    // main sweep: 16 output rows x 4 chunks of 1024 columns, float4 stores
    const int k4 = (t & 3) * 4;        // column offset within 16x16 block
    const int cb_local = t >> 2;       // block-col within chunk (0..63)
    for (int j = 0; j < 16; ++j) {
        const size_t rowbase = (size_t)(r * 16 + j) * LDim + (size_t)seg * 4096;
        for (int chunk = 0; chunk < 4; ++chunk) {
            const int c = seg * 256 + chunk * 64 + cb_local;   // block-col
            const int id = sIdx[c];
            float4 v = make_float4(0.f, 0.f, 0.f, 0.f);
            if (c == r) {
                v = *(const float4*)&sDiag[j * 16 + k4];
            } else if (id != 0) {
                const int e = (id > 0) ? id - 1 : -id - 1;
                const float* A = maps + (size_t)e * 256;            // Mf
                const float* B = A + (size_t)EE * 256;              // Mt
                float4 acc = make_float4(0.f, 0.f, 0.f, 0.f);
                if (id > 0) {
                    // T[j,k] = sum_i Mf[i,j] * Mt[i,k]
                    #pragma unroll
                    for (int i = 0; i < 16; ++i) {
                        const float  aj = A[i * 16 + j];
                        const float4 b4 = *(const float4*)&B[i * 16 + k4];
                        acc.x += aj * b4.x; acc.y += aj * b4.y;
                        acc.z += aj * b4.z; acc.w += aj * b4.w;
                    }
                } else {
                    // T^T[j,k] = sum_i Mf[i,k] * Mt[i,j]
                    #pragma unroll
                    for (int i = 0; i < 16; ++i) {
                        const float  bj = B[i * 16 + j];
                        const float4 a4 = *(const float4*)&A[i * 16 + k4];
                        acc.x += bj * a4.x; acc.y += bj * a4.y;
                        acc.z += bj * a4.z; acc.w += bj * a4.w;
                    }
                }
                const float s = -dinv_r * rsqrtf(degrees[c] * 16.0f + 1.0f);
                v.x = s * acc.x; v.y = s * acc.y;
                v.z = s * acc.z; v.w = s * acc.w;
            }
            *(float4*)&out[rowbase + (size_t)chunk * 1024 + t * 4] = v;
        }
    }
}

extern "C" void kernel_launch(void* const* d_in, const int* in_sizes, int n_in,
                              void* d_out, int out_size, void* d_ws, size_t ws_size,
                              hipStream_t stream) {
    // inputs: [0] adj_mat (unused), [1] degrees f32[N], [2] maps f32[2E*256],
    //         [3] edge_index int[2*2E]
    const float* degrees    = (const float*)d_in[1];
    const float* maps       = (const float*)d_in[2];
    const int*   edge_index = (const int*)d_in[3];
    float* out = (float*)d_out;
    short* idx = (short*)d_ws;   // 2 MB

    zero_idx<<<512, 256, 0, stream>>>((int4*)idx);
    scatter_idx<<<EE / 256, 256, 0, stream>>>(edge_index, idx);
    fused_fill<<<4 * NN, 256, 0, stream>>>(maps, degrees, idx, out);
}

// Round 6
// 1226.082 us; speedup vs baseline: 1.2471x; 1.2471x over previous
//
#include <hip/hip_runtime.h>

// LaplacianBuilder: N=1024, E=16384 triu edges, D=16.
// Output L = 16384^2 f32 = 1 GiB, block-sparse (33792 nonzero 16x16 blocks).
// Round 6 (= round 5 resubmit after GPU-acquisition timeout): single main
// dispatch, three DISJOINT wg roles:
//   [0, 4096)        fill-with-holes: pure zero store stream (nontemporal),
//                    skips nonzero-block locations (mask hoisted, no compute)
//   [4096, 20480)    edge wgs: compute -s*(Mf^T Mt) and its transpose once,
//                    write both off-diagonal blocks
//   [20480, 21504)   diag wgs: scan idx row, accumulate M^T M over incident
//                    directed edges, write diagonal block
// Disjoint addresses => no ordering hazard; every out element written once.

#define NN 1024
#define EE 16384
#define LDim 16384
#define FILL_WGS 4096

typedef float vf4 __attribute__((ext_vector_type(4)));

__global__ __launch_bounds__(256) void zero_idx(int4* __restrict__ idx4) {
    idx4[blockIdx.x * 256 + threadIdx.x] = make_int4(0, 0, 0, 0);   // grid 512
}

__global__ __launch_bounds__(256) void scatter_idx(const int* __restrict__ ei,
                                                   short* __restrict__ idx) {
    const int e = blockIdx.x * 256 + threadIdx.x;   // grid 64 -> e in [0,E)
    const int r = ei[e];             // triu row (r < c)
    const int c = ei[2 * EE + e];    // triu col
    idx[r * NN + c] = (short)(e + 1);
    idx[c * NN + r] = (short)(-(e + 1));
}

__global__ __launch_bounds__(256) void lap_main(
    const float* __restrict__ maps,       // [2E][16][16]
    const float* __restrict__ degrees,    // [N]
    const int*   __restrict__ edge_index, // [2][2E]
    const short* __restrict__ idx,        // [N][N]
    float* __restrict__ out)              // [16384][16384]
{
    const int t = threadIdx.x;
    const int b = blockIdx.x;

    if (b < FILL_WGS) {
        // ---------- zero-fill with holes: wg = (block-row r, quarter seg) ----
        __shared__ short sIdx[NN];
        const int r = b >> 2, seg = b & 3;
        ((int2*)sIdx)[t] = ((const int2*)(idx + (size_t)r * NN))[t];
        __syncthreads();
        const int cb = seg * 256 + (t >> 2);   // this thread's block-col (+64*ch)
        const bool m0 = (sIdx[cb      ] == 0) & (cb       != r);
        const bool m1 = (sIdx[cb +  64] == 0) & (cb +  64 != r);
        const bool m2 = (sIdx[cb + 128] == 0) & (cb + 128 != r);
        const bool m3 = (sIdx[cb + 192] == 0) & (cb + 192 != r);
        const vf4 z = {0.f, 0.f, 0.f, 0.f};
        for (int j = 0; j < 16; ++j) {
            vf4* p = (vf4*)(out + (size_t)(r * 16 + j) * LDim
                                + (size_t)seg * 4096) + t;
            if (m0) __builtin_nontemporal_store(z, p);
            if (m1) __builtin_nontemporal_store(z, p + 256);
            if (m2) __builtin_nontemporal_store(z, p + 512);
            if (m3) __builtin_nontemporal_store(z, p + 768);
        }
    } else if (b < FILL_WGS + EE) {
        // ---------- off-diagonal pair for triu edge e ----------
        const int e = b - FILL_WGS;
        __shared__ float Mf[256];
        __shared__ float Mt[256];
        Mf[t] = maps[(size_t)e * 256 + t];
        Mt[t] = maps[(size_t)(e + EE) * 256 + t];
        const int src = edge_index[e];
        const int dst = edge_index[2 * EE + e];
        __syncthreads();
        const float s = rsqrtf(degrees[src] * 16.f + 1.f) *
                        rsqrtf(degrees[dst] * 16.f + 1.f);
        const int j = t >> 4, k = t & 15;
        float tjk = 0.f, tkj = 0.f;
        #pragma unroll
        for (int i = 0; i < 16; ++i) {
            const float fj = Mf[i * 16 + j];
            const float fk = Mf[i * 16 + k];
            const float gj = Mt[i * 16 + j];
            const float gk = Mt[i * 16 + k];
            tjk += fj * gk;   // T[j,k]
            tkj += fk * gj;   // T[k,j]
        }
        out[(size_t)(src * 16 + j) * LDim + dst * 16 + k] = -s * tjk;
        out[(size_t)(dst * 16 + j) * LDim + src * 16 + k] = -s * tkj;
    } else {
        // ---------- diagonal block for node n ----------
        const int n = b - FILL_WGS - EE;
        __shared__ short sIdx2[NN];
        ((int2*)sIdx2)[t] = ((const int2*)(idx + (size_t)n * NN))[t];
        __syncthreads();
        const int j = t >> 4, k = t & 15;
        float acc = 0.f;
        for (int c = 0; c < NN; ++c) {
            const int id = sIdx2[c];   // same addr for all lanes -> broadcast
            if (id != 0) {
                // directed edge with src==n: maps[e] if n is triu row,
                // maps[e+E] if n is triu col.
                const int m = (id > 0) ? (id - 1) : (-id - 1 + EE);
                const float* __restrict__ M = maps + (size_t)m * 256;
                #pragma unroll
                for (int i = 0; i < 16; ++i)
                    acc += M[i * 16 + j] * M[i * 16 + k];
            }
        }
        const float di = rsqrtf(degrees[n] * 16.f + 1.f);
        out[(size_t)(n * 16 + j) * LDim + n * 16 + k] = acc * di * di;
    }
}

extern "C" void kernel_launch(void* const* d_in, const int* in_sizes, int n_in,
                              void* d_out, int out_size, void* d_ws, size_t ws_size,
                              hipStream_t stream) {
    // inputs: [0] adj_mat (unused), [1] degrees f32[N], [2] maps f32[2E*256],
    //         [3] edge_index int[2*2E]
    const float* degrees    = (const float*)d_in[1];
    const float* maps       = (const float*)d_in[2];
    const int*   edge_index = (const int*)d_in[3];
    float* out = (float*)d_out;
    short* idx = (short*)d_ws;   // 2 MB block-index table

    zero_idx<<<512, 256, 0, stream>>>((int4*)idx);
    scatter_idx<<<EE / 256, 256, 0, stream>>>(edge_index, idx);
    lap_main<<<FILL_WGS + EE + NN, 256, 0, stream>>>(maps, degrees, edge_index,
                                                     idx, out);
}

// Round 7
// 1169.404 us; speedup vs baseline: 1.3075x; 1.0485x over previous
//
#include <hip/hip_runtime.h>

// LaplacianBuilder: N=1024, E=16384 triu edges, D=16.
// Output L = 16384^2 f32 = 1 GiB, block-sparse (33792 nonzero 16x16 blocks).
// Round 7: back to the PROVEN structure (R1: rocclr memset at 6.3 TB/s) with
// the one measured defect removed (8.4M contended atomics -> CSR diag).
//   prep:   zero 1024 counters; build CSR of directed edges (32K atomics on
//           1024 counters, ~5 us)
//   memset: hipMemsetAsync 1 GiB (rocclr fill, measured ~6.3 TB/s)
//   lap_blocks: [0,EE) edge wgs write the two off-diag blocks (no atomics);
//               [EE,EE+NN) diag wgs accumulate M^T M over the node's CSR list
//               with double-buffered LDS (1 barrier/edge, latency hidden).
// Double-write of nonzero blocks vs memset costs ~34 MB extra (~6 us) — far
// cheaper than the write-once schemes measured in R3/R6 (2.2-2.8 TB/s).

#define NN 1024
#define EE 16384
#define LDim 16384
#define CSR_STRIDE 128   // max directed degree headroom (avg 32)

// ws layout: int cnt[1024] | int csr[1024*CSR_STRIDE]  (~516 KB)

__global__ __launch_bounds__(256) void zero_cnt(int* __restrict__ cnt) {
    cnt[blockIdx.x * 256 + threadIdx.x] = 0;            // grid 4
}

__global__ __launch_bounds__(256) void build_csr(const int* __restrict__ ei,
                                                 int* __restrict__ cnt,
                                                 int* __restrict__ csr) {
    const int e = blockIdx.x * 256 + threadIdx.x;       // grid 128 -> e in [0,2E)
    const int n = ei[e];                                // src of directed edge e
    const int slot = atomicAdd(&cnt[n], 1);
    csr[n * CSR_STRIDE + slot] = e;
}

__global__ __launch_bounds__(256) void lap_blocks(
    const float* __restrict__ maps,       // [2E][16][16]
    const float* __restrict__ degrees,    // [N]
    const int*   __restrict__ edge_index, // [2][2E]
    const int*   __restrict__ cnt,        // directed degree per node
    const int*   __restrict__ csr,
    float* __restrict__ out)              // [16384][16384]
{
    const int t = threadIdx.x;
    const int j = t >> 4, k = t & 15;
    const int b = blockIdx.x;

    if (b < EE) {
        // ---------- off-diagonal pair for triu edge b ----------
        __shared__ float Mf[256];
        __shared__ float Mt[256];
        Mf[t] = maps[(size_t)b * 256 + t];
        Mt[t] = maps[(size_t)(b + EE) * 256 + t];
        const int src = edge_index[b];            // triu row (src < dst)
        const int dst = edge_index[2 * EE + b];   // triu col
        __syncthreads();
        const float s = rsqrtf(degrees[src] * 16.f + 1.f) *
                        rsqrtf(degrees[dst] * 16.f + 1.f);
        float tjk = 0.f, tkj = 0.f;
        #pragma unroll
        for (int i = 0; i < 16; ++i) {
            const float fj = Mf[i * 16 + j];   // broadcast (16 lanes/addr)
            const float fk = Mf[i * 16 + k];   // 16 addrs over 16 banks
            const float gj = Mt[i * 16 + j];
            const float gk = Mt[i * 16 + k];
            tjk += fj * gk;   // T[j,k] = sum_i Mf[i,j]*Mt[i,k]
            tkj += fk * gj;   // T[k,j]
        }
        out[(size_t)(src * 16 + j) * LDim + dst * 16 + k] = -s * tjk;
        out[(size_t)(dst * 16 + j) * LDim + src * 16 + k] = -s * tkj;
    } else {
        // ---------- diagonal block for node n (CSR, double-buffered) ----------
        const int n = b - EE;
        const int deg = cnt[n];
        __shared__ float buf[2][256];
        if (deg > 0)
            buf[0][t] = maps[(size_t)csr[n * CSR_STRIDE] * 256 + t];
        float acc = 0.f;
        for (int q = 0; q < deg; ++q) {
            __syncthreads();   // buf[q&1] ready; prior reads of buf[(q+1)&1] done
            if (q + 1 < deg)
                buf[(q + 1) & 1][t] =
                    maps[(size_t)csr[n * CSR_STRIDE + q + 1] * 256 + t];
            const float* __restrict__ M = buf[q & 1];
            #pragma unroll
            for (int i = 0; i < 16; ++i)
                acc += M[i * 16 + j] * M[i * 16 + k];
        }
        const float di2 = 1.f / (degrees[n] * 16.f + 1.f);   // dinv^2
        out[(size_t)(n * 16 + j) * LDim + n * 16 + k] = acc * di2;
    }
}

extern "C" void kernel_launch(void* const* d_in, const int* in_sizes, int n_in,
                              void* d_out, int out_size, void* d_ws, size_t ws_size,
                              hipStream_t stream) {
    // inputs: [0] adj_mat (unused), [1] degrees f32[N], [2] maps f32[2E*256],
    //         [3] edge_index int[2*2E]
    const float* degrees    = (const float*)d_in[1];
    const float* maps       = (const float*)d_in[2];
    const int*   edge_index = (const int*)d_in[3];
    float* out = (float*)d_out;

    int* cnt = (int*)d_ws;
    int* csr = cnt + 1024;

    zero_cnt<<<4, 256, 0, stream>>>(cnt);
    build_csr<<<2 * EE / 256, 256, 0, stream>>>(edge_index, cnt, csr);
    // Bulk zero via rocclr fill — measured ~6.3 TB/s (R1: never in top-5).
    hipMemsetAsync(out, 0, (size_t)out_size * sizeof(float), stream);
    lap_blocks<<<EE + NN, 256, 0, stream>>>(maps, degrees, edge_index, cnt, csr,
                                            out);
}